// Round 2
// baseline (282.516 us; speedup 1.0000x reference)
//
#include <hip/hip_runtime.h>
#include <math.h>

#define MAXDEPTH 5
#define BSZ 512
#define DD 32000           // non-EOS tokens
#define VV (DD + 1)        // + EOS column
#define ALPHA 0.1f

#define SPLIT 4
#define CHUNK (DD / SPLIT)                      // 8000 elements per unit
#define CVEC  (CHUNK / 4)                       // 2000 float4 per unit
#define GRID1 2048                              // 8 blocks/CU exactly
#define UPB   ((MAXDEPTH * BSZ * SPLIT) / GRID1) // 5 units per block, exact
#define WSS   10                                // floats per unit in ws

// Depth-dependent KL target parameters: a = 1/denom(depth), t_ne = (1-a)/D.
__device__ __forceinline__ void depth_target(int depth, float* a_out, float* tne_out) {
    double dd = (double)DD;
    double denom = 0.0, p = 1.0;
    const int top = MAXDEPTH - depth;
    for (int i = 0; i <= top; ++i) { denom += p; p *= dd; }
    const float a = (float)(1.0 / denom);
    *a_out = a;
    *tne_out = (1.0f - a) / (float)DD;
}

// Pass 1: 2048 persistent blocks; each owns 5 contiguous quarter-row chunks.
// Per chunk, reduces 7 sums (T,U,P,Q,A,B,KL) + gumbel argmax; writes 9 floats.
//   T = sum e^(lp+lq), U = sum e^(lp+lq+ln), P = sum e1*(lp+lq),
//   Q = sum e12*(lp+lq), A = sum e2*ln, B = sum e12*ln, KL = sum(lp+ln+lq)
// Derived later: S1 = T-U, S2 = P-Q, last = T*A - B.
__global__ __launch_bounds__(256) void pgr_pass1(
    const float* __restrict__ lp_all, const float* __restrict__ ln_all,
    const float* __restrict__ lq_all, const float* __restrict__ gm_all,
    const int* __restrict__ st_all, float* __restrict__ ws)
{
    const int tid = threadIdx.x;
    const int lane = tid & 63;
    const int wv = tid >> 6;
    __shared__ float sh[4][9];
    __shared__ int shi[4];

    const int u0 = blockIdx.x * UPB;
    for (int uu = 0; uu < UPB; ++uu) {
        const int u = u0 + uu;
        const int dr = u / SPLIT;            // depth*BSZ + row
        const int s = u % SPLIT;             // chunk within row
        const size_t rowoff = (size_t)dr * VV;
        const float* __restrict__ lp  = lp_all + rowoff + (size_t)s * CHUNK;
        const float* __restrict__ lnv = ln_all + rowoff + (size_t)s * CHUNK;
        const float* __restrict__ lq  = lq_all + rowoff + (size_t)s * CHUNK;
        const float* __restrict__ gm  = gm_all + (size_t)dr * DD + (size_t)s * CHUNK;
        const int st = st_all[dr];
        const int gbase = s * CHUNK;

        float T = 0.f, U = 0.f, P = 0.f, Q = 0.f, A = 0.f, B = 0.f, KL = 0.f;
        float amax = -INFINITY;
        int aidx = 0x7fffffff;

#define ELEM(pv, nv, qv, gv, gidx) do {                                   \
        const float lpq = (pv) + (qv);                                    \
        KL += lpq + (nv);                                                 \
        const float e1 = __expf(lpq);                                     \
        const float e2 = __expf(nv);                                      \
        const float e12 = e1 * e2;                                        \
        T += e1; U += e12;                                                \
        P = fmaf(e1, lpq, P); Q = fmaf(e12, lpq, Q);                      \
        A = fmaf(e2, (nv), A); B = fmaf(e12, (nv), B);                    \
        const float sel = (st == 0) ? (pv) : ((st == 1) ? (nv) : (qv));   \
        const float sv = sel + (gv);                                      \
        if (sv > amax) { amax = sv; aidx = (gidx); }                      \
    } while (0)

        // Two float4-groups per stream per iteration: 8 independent loads
        // in flight before the dependent exp chains begin.
        for (int i = tid; i < CVEC; i += 512) {
            const int j = i + 256;
            const bool jb = (j < CVEC);
            const float4 pa = ((const float4*)lp)[i];
            const float4 na = ((const float4*)lnv)[i];
            const float4 qa = ((const float4*)lq)[i];
            const float4 ga = ((const float4*)gm)[i];
            float4 pb, nb, qb, gb;
            if (jb) {
                pb = ((const float4*)lp)[j];
                nb = ((const float4*)lnv)[j];
                qb = ((const float4*)lq)[j];
                gb = ((const float4*)gm)[j];
            }
            ELEM(pa.x, na.x, qa.x, ga.x, gbase + i * 4 + 0);
            ELEM(pa.y, na.y, qa.y, ga.y, gbase + i * 4 + 1);
            ELEM(pa.z, na.z, qa.z, ga.z, gbase + i * 4 + 2);
            ELEM(pa.w, na.w, qa.w, ga.w, gbase + i * 4 + 3);
            if (jb) {
                ELEM(pb.x, nb.x, qb.x, gb.x, gbase + j * 4 + 0);
                ELEM(pb.y, nb.y, qb.y, gb.y, gbase + j * 4 + 1);
                ELEM(pb.z, nb.z, qb.z, gb.z, gbase + j * 4 + 2);
                ELEM(pb.w, nb.w, qb.w, gb.w, gbase + j * 4 + 3);
            }
        }
#undef ELEM

#pragma unroll
        for (int o = 32; o > 0; o >>= 1) {
            T += __shfl_down(T, o); U += __shfl_down(U, o);
            P += __shfl_down(P, o); Q += __shfl_down(Q, o);
            A += __shfl_down(A, o); B += __shfl_down(B, o);
            KL += __shfl_down(KL, o);
            const float ov = __shfl_down(amax, o);
            const int oi = __shfl_down(aidx, o);
            if (ov > amax || (ov == amax && oi < aidx)) { amax = ov; aidx = oi; }
        }
        if (lane == 0) {
            sh[wv][0] = T; sh[wv][1] = U; sh[wv][2] = P; sh[wv][3] = Q;
            sh[wv][4] = A; sh[wv][5] = B; sh[wv][6] = KL; sh[wv][7] = amax;
            shi[wv] = aidx;
        }
        __syncthreads();
        if (tid == 0) {
            for (int w2 = 1; w2 < 4; ++w2) {
                T += sh[w2][0]; U += sh[w2][1]; P += sh[w2][2]; Q += sh[w2][3];
                A += sh[w2][4]; B += sh[w2][5]; KL += sh[w2][6];
                const float ov = sh[w2][7]; const int oi = shi[w2];
                if (ov > amax || (ov == amax && oi < aidx)) { amax = ov; aidx = oi; }
            }
            float* o = ws + (size_t)u * WSS;
            o[0] = T; o[1] = U; o[2] = P; o[3] = Q; o[4] = A; o[5] = B;
            o[6] = KL; o[7] = amax; o[8] = __int_as_float(aidx);
        }
        __syncthreads();   // protect sh[] before next unit
    }
}

// Pass 2: single block, one thread per row. Combines chunk partials, adds
// the EOS column, gathers at argmax, kl batch-mean per depth, prefix logcur,
// backward recursion, final mean.
__global__ __launch_bounds__(BSZ) void pgr_pass2(
    const float* __restrict__ ws,
    const float* __restrict__ lp_all, const float* __restrict__ ln_all,
    const float* __restrict__ lq_all, const int* __restrict__ st_all,
    float* __restrict__ out)
{
    const int r = threadIdx.x;      // row
    __shared__ float red[BSZ];
    __shared__ float klmean_sh;

    float base[MAXDEPTH], smv[MAXDEPTH];
    float logcur = 0.f;

    for (int depth = 0; depth < MAXDEPTH; ++depth) {
        const int dr = depth * BSZ + r;
        float T = 0.f, U = 0.f, P = 0.f, Q = 0.f, A = 0.f, B = 0.f, KL = 0.f;
        float amax = -INFINITY;
        int aidx = 0x7fffffff;
#pragma unroll
        for (int s = 0; s < SPLIT; ++s) {
            const float* o = ws + ((size_t)dr * SPLIT + s) * WSS;
            T += o[0]; U += o[1]; P += o[2]; Q += o[3];
            A += o[4]; B += o[5]; KL += o[6];
            const float ov = o[7]; const int oi = __float_as_int(o[8]);
            if (ov > amax || (ov == amax && oi < aidx)) { amax = ov; aidx = oi; }
        }

        // EOS column (not part of argmax)
        const size_t rowoff = (size_t)dr * VV;
        const float pe = lp_all[rowoff + DD];
        const float ne = ln_all[rowoff + DD];
        const float qe = lq_all[rowoff + DD];
        {
            const float lpq = pe + qe;
            const float e1 = __expf(lpq);
            const float e2 = __expf(ne);
            const float e12 = e1 * e2;
            T += e1; U += e12;
            P = fmaf(e1, lpq, P); Q = fmaf(e12, lpq, Q);
            A = fmaf(e2, ne, A); B = fmaf(e12, ne, B);
        }
        const float S1 = T - U;
        const float S2 = P - Q;
        const float last = T * A - B;
        const float kleos = pe + ne + qe;

        float a, tne;
        depth_target(depth, &a, &tne);
        const float klrow = tne * KL + a * kleos;

        red[r] = klrow;
        __syncthreads();
        for (int s = BSZ / 2; s > 0; s >>= 1) {
            if (r < s) red[r] += red[r + s];
            __syncthreads();
        }
        if (r == 0) klmean_sh = red[0] / (float)BSZ;
        __syncthreads();
        const float klmean = klmean_sh;
        __syncthreads();   // protect red[] before next depth

        // C = sum_v t*log t
        const float C = (float)DD * tne * logf(tne) + a * logf(a);
        const float kl = 3.f * C - klmean;

        // gather at sampled token
        const int nxt = aidx;
        const float lpn = lp_all[rowoff + nxt];
        const float lnn = ln_all[rowoff + nxt];
        const float lqn = lq_all[rowoff + nxt];
        const float sum3n = lpn + lnn + lqn;
        const int st = st_all[dr];
        const float smlog = (st == 0) ? (lnn + lqn)
                          : (st == 1) ? (lpn + lqn)
                                      : (lpn + lnn);

        base[depth] = S1 * logcur + S2 + last - ALPHA * kl;
        smv[depth] = __expf(smlog);
        logcur += sum3n;
    }

    // u_seq == 1 always: argmax is over the D non-EOS tokens, never EOS.
    float R = base[MAXDEPTH - 1];
    for (int depth = MAXDEPTH - 2; depth >= 0; --depth)
        R = R * smv[depth] + base[depth];

    red[r] = R;
    __syncthreads();
    for (int s = BSZ / 2; s > 0; s >>= 1) {
        if (r < s) red[r] += red[r + s];
        __syncthreads();
    }
    if (r == 0) out[0] = -red[0] / (float)BSZ;
}

extern "C" void kernel_launch(void* const* d_in, const int* in_sizes, int n_in,
                              void* d_out, int out_size, void* d_ws, size_t ws_size,
                              hipStream_t stream) {
    const float* lp = (const float*)d_in[0];   // logp_pos (5,512,32001)
    const float* ln = (const float*)d_in[1];   // logp_neg
    const float* lq = (const float*)d_in[2];   // logp_q
    const float* gm = (const float*)d_in[3];   // gumbel   (5,512,32000)
    const int*   st = (const int*)d_in[4];     // sampling_target (5,512)
    float* ws  = (float*)d_ws;                 // 10240 * 10 floats = 409.6 KB
    float* out = (float*)d_out;

    pgr_pass1<<<GRID1, 256, 0, stream>>>(lp, ln, lq, gm, st, ws);
    pgr_pass2<<<1, BSZ, 0, stream>>>(ws, lp, ln, lq, st, out);
}

// Round 3
// 240.881 us; speedup vs baseline: 1.1728x; 1.1728x over previous
//
#include <hip/hip_runtime.h>
#include <math.h>

#define MAXDEPTH 5
#define BSZ 512
#define DD 32000           // non-EOS tokens
#define VV (DD + 1)        // + EOS column
#define ALPHA 0.1f

// Depth-dependent KL target parameters: a = 1/denom(depth), t_ne = (1-a)/D.
// denom(depth) = sum_{i=0}^{MAXDEPTH-depth} D^i
__device__ __forceinline__ void depth_target(int depth, float* a_out, float* tne_out) {
    double dd = (double)DD;
    double denom = 0.0, p = 1.0;
    const int top = MAXDEPTH - depth;
    for (int i = 0; i <= top; ++i) { denom += p; p *= dd; }
    const float a = (float)(1.0 / denom);
    *a_out = a;
    *tne_out = (1.0f - a) / (float)DD;
}

// Pass 1: one block per (depth,row). Streams 3 logp rows + gumbel row with
// 16B-aligned float4 body (scalar head/tail peel for the odd VV row stride),
// reduces S1, S2, T, A, B, KL-sum and the gumbel argmax, finalizes the row
// (EOS column + cache-hot gather at argmax) and writes 6 floats.
__global__ __launch_bounds__(256) void pgr_pass1(
    const float* __restrict__ lp_all, const float* __restrict__ ln_all,
    const float* __restrict__ lq_all, const float* __restrict__ gm_all,
    const int* __restrict__ st_all, float* __restrict__ ws)
{
    const int bid = blockIdx.x;              // depth*BSZ + row
    const int tid = threadIdx.x;
    const size_t rowoff = (size_t)bid * VV;
    const float* __restrict__ lp  = lp_all + rowoff;
    const float* __restrict__ lnv = ln_all + rowoff;
    const float* __restrict__ lq  = lq_all + rowoff;
    const float* __restrict__ gm  = gm_all + (size_t)bid * DD;
    const int st = st_all[bid];

    // alignment peel: make the 3 logp streams 16B-aligned in the vector body
    const int mis  = (int)(rowoff & 3);      // misalignment in floats
    const int peel = (4 - mis) & 3;          // scalar head [0, peel)
    const int nvec = (DD - peel) / 4;        // aligned float4 body
    const int tail0 = peel + 4 * nvec;       // scalar tail [tail0, DD)

    float S1 = 0.f, S2 = 0.f, T = 0.f, A = 0.f, B = 0.f, KL = 0.f;
    float amax = -INFINITY;
    int aidx = 0x7fffffff;

#define ELEM(pv, nv, qv, gv, gidx) do {                                   \
        const float lpq = (pv) + (qv);                                    \
        const float e1 = __expf(lpq);                                     \
        const float e2 = __expf(nv);                                      \
        const float w  = e1 * (1.f - e2);                                 \
        S1 += w;                                                          \
        S2 = fmaf(w, lpq, S2);                                            \
        T  += e1;                                                         \
        A  = fmaf(e2, (nv), A);                                           \
        B  = fmaf(e2 * e1, (nv), B);                                      \
        KL += lpq + (nv);                                                 \
        const float sel = (st == 0) ? (pv) : ((st == 1) ? (nv) : (qv));   \
        const float sv  = sel + (gv);                                     \
        if (sv > amax) { amax = sv; aidx = (gidx); }                      \
    } while (0)

    // scalar head + tail on thread 0 (<= 4 elements total)
    if (tid == 0) {
        for (int e = 0; e < peel; ++e)
            ELEM(lp[e], lnv[e], lq[e], gm[e], e);
        for (int e = tail0; e < DD; ++e)
            ELEM(lp[e], lnv[e], lq[e], gm[e], e);
    }

    // aligned vector body
    const float* __restrict__ lpA = lp  + peel;
    const float* __restrict__ lnA = lnv + peel;
    const float* __restrict__ lqA = lq  + peel;
    const float* __restrict__ gmA = gm  + peel;   // 4B-aligned only; 1 of 4 streams
    for (int i = tid; i < nvec; i += 256) {
        const float4 p4 = ((const float4*)lpA)[i];
        const float4 n4 = ((const float4*)lnA)[i];
        const float4 q4 = ((const float4*)lqA)[i];
        const float4 g4 = *(const float4*)(gmA + 4 * (size_t)i);
        const int gb = peel + i * 4;
        ELEM(p4.x, n4.x, q4.x, g4.x, gb + 0);
        ELEM(p4.y, n4.y, q4.y, g4.y, gb + 1);
        ELEM(p4.z, n4.z, q4.z, g4.z, gb + 2);
        ELEM(p4.w, n4.w, q4.w, g4.w, gb + 3);
    }
#undef ELEM

    // wave (64-lane) reduction
    const int lane = tid & 63;
    const int wv   = tid >> 6;
#pragma unroll
    for (int o = 32; o > 0; o >>= 1) {
        S1 += __shfl_down(S1, o);
        S2 += __shfl_down(S2, o);
        T  += __shfl_down(T, o);
        A  += __shfl_down(A, o);
        B  += __shfl_down(B, o);
        KL += __shfl_down(KL, o);
        const float ov = __shfl_down(amax, o);
        const int   oi = __shfl_down(aidx, o);
        if (ov > amax || (ov == amax && oi < aidx)) { amax = ov; aidx = oi; }
    }

    __shared__ float sh[4][7];
    __shared__ int   shi[4];
    if (lane == 0) {
        sh[wv][0] = S1; sh[wv][1] = S2; sh[wv][2] = T; sh[wv][3] = A;
        sh[wv][4] = B;  sh[wv][5] = KL; sh[wv][6] = amax;
        shi[wv] = aidx;
    }
    __syncthreads();

    if (tid == 0) {
        for (int w2 = 1; w2 < 4; ++w2) {
            S1 += sh[w2][0]; S2 += sh[w2][1]; T += sh[w2][2];
            A  += sh[w2][3]; B  += sh[w2][4]; KL += sh[w2][5];
            const float ov = sh[w2][6]; const int oi = shi[w2];
            if (ov > amax || (ov == amax && oi < aidx)) { amax = ov; aidx = oi; }
        }
        // EOS column (v = DD): in the sums but not the argmax.
        const float pe = lp[DD], ne = lnv[DD], qe = lq[DD];
        {
            const float lpq = pe + qe;
            const float e1 = __expf(lpq);
            const float e2 = __expf(ne);
            const float w  = e1 * (1.f - e2);
            S1 += w; S2 = fmaf(w, lpq, S2); T += e1;
            A = fmaf(e2, ne, A); B = fmaf(e2 * e1, ne, B);
        }
        const float kleos = pe + ne + qe;
        const float last  = T * A - B;

        // cache-hot gather at the sampled token
        const int nxt   = aidx;
        const float lpn = lp[nxt], lnn = lnv[nxt], lqn = lq[nxt];
        const float sum3n = lpn + lnn + lqn;
        const float smlog = (st == 0) ? (lnn + lqn)
                          : (st == 1) ? (lpn + lqn)
                                      : (lpn + lnn);
        const float sm = __expf(smlog);

        const int depth = bid / BSZ;
        float a, tne;
        depth_target(depth, &a, &tne);
        const float klrow = tne * KL + a * kleos;

        float* o = ws + (size_t)bid * 6;
        o[0] = S1; o[1] = S2; o[2] = last; o[3] = klrow; o[4] = sm; o[5] = sum3n;
    }
}

// Pass 2: single block, one thread per row. kl batch-mean per depth,
// prefix logcur, backward recursion, final mean. Reads only ws (61 KB).
__global__ __launch_bounds__(BSZ) void pgr_pass2(
    const float* __restrict__ ws, float* __restrict__ out)
{
    const int r = threadIdx.x;      // row
    __shared__ float red[BSZ];
    __shared__ float klmean_sh;

    float base[MAXDEPTH], smv[MAXDEPTH];
    float logcur = 0.f;

    for (int depth = 0; depth < MAXDEPTH; ++depth) {
        const float* o = ws + ((size_t)depth * BSZ + r) * 6;
        const float S1 = o[0], S2 = o[1], last = o[2];
        const float klrow = o[3], sm = o[4], sum3n = o[5];

        red[r] = klrow;
        __syncthreads();
        for (int s = BSZ / 2; s > 0; s >>= 1) {
            if (r < s) red[r] += red[r + s];
            __syncthreads();
        }
        if (r == 0) klmean_sh = red[0] / (float)BSZ;
        __syncthreads();
        const float klmean = klmean_sh;
        __syncthreads();   // protect red[] before next depth's write

        float a, tne;
        depth_target(depth, &a, &tne);
        // C = sum_v t*log t  (D identical non-EOS entries + the EOS entry)
        const float C = (float)DD * tne * logf(tne) + a * logf(a);
        const float kl = 3.f * C - klmean;

        base[depth] = S1 * logcur + S2 + last - ALPHA * kl;
        smv[depth]  = sm;
        logcur += sum3n;
    }

    // u_seq == 1 always: argmax is over the D non-EOS tokens, never EOS.
    float R = base[MAXDEPTH - 1];
    for (int depth = MAXDEPTH - 2; depth >= 0; --depth)
        R = R * smv[depth] + base[depth];

    red[r] = R;
    __syncthreads();
    for (int s = BSZ / 2; s > 0; s >>= 1) {
        if (r < s) red[r] += red[r + s];
        __syncthreads();
    }
    if (r == 0) out[0] = -red[0] / (float)BSZ;
}

extern "C" void kernel_launch(void* const* d_in, const int* in_sizes, int n_in,
                              void* d_out, int out_size, void* d_ws, size_t ws_size,
                              hipStream_t stream) {
    const float* lp = (const float*)d_in[0];   // logp_pos (5,512,32001)
    const float* ln = (const float*)d_in[1];   // logp_neg
    const float* lq = (const float*)d_in[2];   // logp_q
    const float* gm = (const float*)d_in[3];   // gumbel   (5,512,32000)
    const int*   st = (const int*)d_in[4];     // sampling_target (5,512)
    float* ws  = (float*)d_ws;                 // 2560 * 6 floats = 61.4 KB
    float* out = (float*)d_out;                // scalar loss

    pgr_pass1<<<MAXDEPTH * BSZ, 256, 0, stream>>>(lp, ln, lq, gm, st, ws);
    pgr_pass2<<<1, BSZ, 0, stream>>>(ws, out);
}

// Round 4
// 235.500 us; speedup vs baseline: 1.1996x; 1.0228x over previous
//
#include <hip/hip_runtime.h>
#include <math.h>

#define MAXDEPTH 5
#define BSZ 512
#define DD 32000           // non-EOS tokens
#define VV (DD + 1)        // + EOS column
#define ALPHA 0.1f

// Depth-dependent KL target parameters: a = 1/denom(depth), t_ne = (1-a)/D.
__device__ __forceinline__ void depth_target(int depth, float* a_out, float* tne_out) {
    double dd = (double)DD;
    double denom = 0.0, p = 1.0;
    const int top = MAXDEPTH - depth;
    for (int i = 0; i <= top; ++i) { denom += p; p *= dd; }
    const float a = (float)(1.0 / denom);
    *a_out = a;
    *tne_out = (1.0f - a) / (float)DD;
}

// Pass 1: one block per (depth,row). Streams 3 logp rows + gumbel row.
// This round's single variable: per-thread 2x-float4 STREAM-MAJOR bursts
// (each wave pulls 2KB contiguous per stream before switching streams) to
// improve DRAM page locality across the ~8K concurrent streams.
__global__ __launch_bounds__(256) void pgr_pass1(
    const float* __restrict__ lp_all, const float* __restrict__ ln_all,
    const float* __restrict__ lq_all, const float* __restrict__ gm_all,
    const int* __restrict__ st_all, float* __restrict__ ws)
{
    const int bid = blockIdx.x;              // depth*BSZ + row
    const int tid = threadIdx.x;
    const size_t rowoff = (size_t)bid * VV;
    const float* __restrict__ lp  = lp_all + rowoff;
    const float* __restrict__ lnv = ln_all + rowoff;
    const float* __restrict__ lq  = lq_all + rowoff;
    const float* __restrict__ gm  = gm_all + (size_t)bid * DD;
    const int st = st_all[bid];

    // alignment peel: 16B-aligned vector body for the 3 logp streams
    const int mis  = (int)(rowoff & 3);
    const int peel = (4 - mis) & 3;
    const int nvec = (DD - peel) / 4;
    const int tail0 = peel + 4 * nvec;

    float S1 = 0.f, S2 = 0.f, T = 0.f, A = 0.f, B = 0.f, KL = 0.f;
    float amax = -INFINITY;
    int aidx = 0x7fffffff;

#define ELEM(pv, nv, qv, gv, gidx) do {                                   \
        const float lpq = (pv) + (qv);                                    \
        const float e1 = __expf(lpq);                                     \
        const float e2 = __expf(nv);                                      \
        const float w  = e1 * (1.f - e2);                                 \
        S1 += w;                                                          \
        S2 = fmaf(w, lpq, S2);                                            \
        T  += e1;                                                         \
        A  = fmaf(e2, (nv), A);                                           \
        B  = fmaf(e2 * e1, (nv), B);                                      \
        KL += lpq + (nv);                                                 \
        const float sel = (st == 0) ? (pv) : ((st == 1) ? (nv) : (qv));   \
        const float sv  = sel + (gv);                                     \
        if (sv > amax) { amax = sv; aidx = (gidx); }                      \
    } while (0)

    // scalar head + tail on thread 0 (<= 4 elements total)
    if (tid == 0) {
        for (int e = 0; e < peel; ++e)
            ELEM(lp[e], lnv[e], lq[e], gm[e], e);
        for (int e = tail0; e < DD; ++e)
            ELEM(lp[e], lnv[e], lq[e], gm[e], e);
    }

    const float* __restrict__ lpA = lp  + peel;
    const float* __restrict__ lnA = lnv + peel;
    const float* __restrict__ lqA = lq  + peel;
    const float* __restrict__ gmA = gm  + peel;

    // stream-major paired loads: thread handles float4 indices {i, i+1}
    for (int i = 2 * tid; i < nvec; i += 512) {
        const int j = i + 1;
        const bool jb = (j < nvec);
        const float4 p0 = ((const float4*)lpA)[i];
        const float4 p1 = jb ? ((const float4*)lpA)[j] : make_float4(0, 0, 0, 0);
        const float4 n0 = ((const float4*)lnA)[i];
        const float4 n1 = jb ? ((const float4*)lnA)[j] : make_float4(0, 0, 0, 0);
        const float4 q0 = ((const float4*)lqA)[i];
        const float4 q1 = jb ? ((const float4*)lqA)[j] : make_float4(0, 0, 0, 0);
        const float4 g0 = *(const float4*)(gmA + 4 * (size_t)i);
        const float4 g1 = jb ? *(const float4*)(gmA + 4 * (size_t)j)
                             : make_float4(0, 0, 0, 0);
        const int gb = peel + i * 4;
        ELEM(p0.x, n0.x, q0.x, g0.x, gb + 0);
        ELEM(p0.y, n0.y, q0.y, g0.y, gb + 1);
        ELEM(p0.z, n0.z, q0.z, g0.z, gb + 2);
        ELEM(p0.w, n0.w, q0.w, g0.w, gb + 3);
        if (jb) {
            ELEM(p1.x, n1.x, q1.x, g1.x, gb + 4);
            ELEM(p1.y, n1.y, q1.y, g1.y, gb + 5);
            ELEM(p1.z, n1.z, q1.z, g1.z, gb + 6);
            ELEM(p1.w, n1.w, q1.w, g1.w, gb + 7);
        }
    }
#undef ELEM

    // wave (64-lane) reduction
    const int lane = tid & 63;
    const int wv   = tid >> 6;
#pragma unroll
    for (int o = 32; o > 0; o >>= 1) {
        S1 += __shfl_down(S1, o);
        S2 += __shfl_down(S2, o);
        T  += __shfl_down(T, o);
        A  += __shfl_down(A, o);
        B  += __shfl_down(B, o);
        KL += __shfl_down(KL, o);
        const float ov = __shfl_down(amax, o);
        const int   oi = __shfl_down(aidx, o);
        if (ov > amax || (ov == amax && oi < aidx)) { amax = ov; aidx = oi; }
    }

    __shared__ float sh[4][7];
    __shared__ int   shi[4];
    if (lane == 0) {
        sh[wv][0] = S1; sh[wv][1] = S2; sh[wv][2] = T; sh[wv][3] = A;
        sh[wv][4] = B;  sh[wv][5] = KL; sh[wv][6] = amax;
        shi[wv] = aidx;
    }
    __syncthreads();

    if (tid == 0) {
        for (int w2 = 1; w2 < 4; ++w2) {
            S1 += sh[w2][0]; S2 += sh[w2][1]; T += sh[w2][2];
            A  += sh[w2][3]; B  += sh[w2][4]; KL += sh[w2][5];
            const float ov = sh[w2][6]; const int oi = shi[w2];
            if (ov > amax || (ov == amax && oi < aidx)) { amax = ov; aidx = oi; }
        }
        // EOS column (v = DD): in the sums but not the argmax.
        const float pe = lp[DD], ne = lnv[DD], qe = lq[DD];
        {
            const float lpq = pe + qe;
            const float e1 = __expf(lpq);
            const float e2 = __expf(ne);
            const float w  = e1 * (1.f - e2);
            S1 += w; S2 = fmaf(w, lpq, S2); T += e1;
            A = fmaf(e2, ne, A); B = fmaf(e2 * e1, ne, B);
        }
        const float kleos = pe + ne + qe;
        const float last  = T * A - B;

        // cache-hot gather at the sampled token
        const int nxt   = aidx;
        const float lpn = lp[nxt], lnn = lnv[nxt], lqn = lq[nxt];
        const float sum3n = lpn + lnn + lqn;
        const float smlog = (st == 0) ? (lnn + lqn)
                          : (st == 1) ? (lpn + lqn)
                                      : (lpn + lnn);
        const float sm = __expf(smlog);

        const int depth = bid / BSZ;
        float a, tne;
        depth_target(depth, &a, &tne);
        const float klrow = tne * KL + a * kleos;

        float* o = ws + (size_t)bid * 6;
        o[0] = S1; o[1] = S2; o[2] = last; o[3] = klrow; o[4] = sm; o[5] = sum3n;
    }
}

// Pass 2: single block, one thread per row. kl batch-mean per depth,
// prefix logcur, backward recursion, final mean. Reads only ws (61 KB).
__global__ __launch_bounds__(BSZ) void pgr_pass2(
    const float* __restrict__ ws, float* __restrict__ out)
{
    const int r = threadIdx.x;      // row
    __shared__ float red[BSZ];
    __shared__ float klmean_sh;

    float base[MAXDEPTH], smv[MAXDEPTH];
    float logcur = 0.f;

    for (int depth = 0; depth < MAXDEPTH; ++depth) {
        const float* o = ws + ((size_t)depth * BSZ + r) * 6;
        const float S1 = o[0], S2 = o[1], last = o[2];
        const float klrow = o[3], sm = o[4], sum3n = o[5];

        red[r] = klrow;
        __syncthreads();
        for (int s = BSZ / 2; s > 0; s >>= 1) {
            if (r < s) red[r] += red[r + s];
            __syncthreads();
        }
        if (r == 0) klmean_sh = red[0] / (float)BSZ;
        __syncthreads();
        const float klmean = klmean_sh;
        __syncthreads();   // protect red[] before next depth's write

        float a, tne;
        depth_target(depth, &a, &tne);
        const float C = (float)DD * tne * logf(tne) + a * logf(a);
        const float kl = 3.f * C - klmean;

        base[depth] = S1 * logcur + S2 + last - ALPHA * kl;
        smv[depth]  = sm;
        logcur += sum3n;
    }

    // u_seq == 1 always: argmax is over the D non-EOS tokens, never EOS.
    float R = base[MAXDEPTH - 1];
    for (int depth = MAXDEPTH - 2; depth >= 0; --depth)
        R = R * smv[depth] + base[depth];

    red[r] = R;
    __syncthreads();
    for (int s = BSZ / 2; s > 0; s >>= 1) {
        if (r < s) red[r] += red[r + s];
        __syncthreads();
    }
    if (r == 0) out[0] = -red[0] / (float)BSZ;
}

extern "C" void kernel_launch(void* const* d_in, const int* in_sizes, int n_in,
                              void* d_out, int out_size, void* d_ws, size_t ws_size,
                              hipStream_t stream) {
    const float* lp = (const float*)d_in[0];   // logp_pos (5,512,32001)
    const float* ln = (const float*)d_in[1];   // logp_neg
    const float* lq = (const float*)d_in[2];   // logp_q
    const float* gm = (const float*)d_in[3];   // gumbel   (5,512,32000)
    const int*   st = (const int*)d_in[4];     // sampling_target (5,512)
    float* ws  = (float*)d_ws;                 // 2560 * 6 floats = 61.4 KB
    float* out = (float*)d_out;                // scalar loss

    pgr_pass1<<<MAXDEPTH * BSZ, 256, 0, stream>>>(lp, ln, lq, gm, st, ws);
    pgr_pass2<<<1, BSZ, 0, stream>>>(ws, out);
}